// Round 10
// baseline (245.999 us; speedup 1.0000x reference)
//
#include <hip/hip_runtime.h>

// Problem constants (B,H,W,C = 8,64,64,256; S = H*W)
#define NB   8
#define SS   4096
#define CC   256
#define NG   32
#define CPG  8
#define EPSV 1e-6f
#define MTOT (NB * SS)   // 32768 rows

typedef short bf16x8 __attribute__((ext_vector_type(8)));
typedef unsigned short u16x8 __attribute__((ext_vector_type(8)));
typedef float f32x4  __attribute__((ext_vector_type(4)));
typedef float f32x16 __attribute__((ext_vector_type(16)));
typedef int   i32x4  __attribute__((ext_vector_type(4)));
typedef int   i32x8  __attribute__((ext_vector_type(8)));
typedef unsigned char u8;

typedef __attribute__((address_space(1))) const unsigned int as1_u32;
typedef __attribute__((address_space(3))) unsigned int as3_u32;

__device__ __forceinline__ unsigned short f2bf(float f) {
  unsigned int u = __builtin_bit_cast(unsigned int, f);
  u = (u + 0x7FFFu + ((u >> 16) & 1u)) >> 16;
  return (unsigned short)u;
}
__device__ __forceinline__ u8 f2fp8(float f) {
  return (u8)(__builtin_amdgcn_cvt_pk_fp8_f32(f, f, 0, 0) & 0xFF);
}
__device__ __forceinline__ void dma16(const u8* src, u8* lds) {
  __builtin_amdgcn_global_load_lds((as1_u32*)src, (as3_u32*)lds, 16, 0, 0);
}
__device__ __forceinline__ float fast_exp2(float x) {
#if __has_builtin(__builtin_amdgcn_exp2f)
  return __builtin_amdgcn_exp2f(x);   // bare v_exp_f32
#else
  return exp2f(x);
#endif
}

// Counted-vmcnt barrier (T3/T4): each wave waits its OWN oldest DMAs (FIFO,
// m135), THEN crosses the barrier -> all waves' counted loads visible in LDS.
// sched_barrier pins ordering (rule 18).
#define CV_BARRIER(N)                                              \
  do {                                                             \
    asm volatile("s_waitcnt vmcnt(" #N ")" ::: "memory");          \
    __builtin_amdgcn_s_barrier();                                  \
    __builtin_amdgcn_sched_barrier(0);                             \
  } while (0)

// ---------------- GroupNorm stats, stage 1: coalesced partials ----------------
__global__ __launch_bounds__(256) void gn_stats_part_kernel(
    const float* __restrict__ x, float* __restrict__ part) {
  const int b = blockIdx.x >> 5, slice = blockIdx.x & 31;
  const int tid = threadIdx.x;
  const int g = tid & 31;            // group
  const int p8 = tid >> 5;           // pos sub-index 0..7
  const float* base = x + ((size_t)(b * SS + slice * 128 + p8) * CC + g * CPG);
  float s = 0.f, ss = 0.f;
#pragma unroll
  for (int it = 0; it < 16; it++) {
    const float4* p = (const float4*)(base + (size_t)it * 8 * CC);
    float4 a = p[0], c = p[1];
    s  += (a.x + a.y) + (a.z + a.w) + (c.x + c.y) + (c.z + c.w);
    ss += (a.x*a.x + a.y*a.y) + (a.z*a.z + a.w*a.w)
        + (c.x*c.x + c.y*c.y) + (c.z*c.z + c.w*c.w);
  }
  s  += __shfl_xor(s, 32);
  ss += __shfl_xor(ss, 32);
  __shared__ float lsum[4][32], lssum[4][32];
  const int wv = tid >> 6, lane = tid & 63;
  if (lane < 32) { lsum[wv][lane] = s; lssum[wv][lane] = ss; }
  __syncthreads();
  if (tid < 32) {
    float ts  = (lsum[0][tid] + lsum[1][tid]) + (lsum[2][tid] + lsum[3][tid]);
    float tss = (lssum[0][tid] + lssum[1][tid]) + (lssum[2][tid] + lssum[3][tid]);
    float* dst = part + ((size_t)(b * 32 + tid) * 32 + slice) * 2;
    dst[0] = ts; dst[1] = tss;
  }
}

// ---------------- Weight prep (+ fused gn_stats finalize at y==4) ----------------
__global__ __launch_bounds__(256) void prep_wt_kernel(
    const float* __restrict__ w0, const float* __restrict__ w1,
    const float* __restrict__ w2, const float* __restrict__ w3,
    unsigned short* __restrict__ wt,
    const float* __restrict__ part, float* __restrict__ stats) {
  __shared__ float t[64][68];
  if (blockIdx.y == 4) {
    if (blockIdx.x == 0) {
      const int bg = threadIdx.x;   // b*32+g, 0..255
      const float* src = part + (size_t)bg * 64;
      float s = 0.f, ss = 0.f;
#pragma unroll
      for (int sl = 0; sl < 32; sl++) { s += src[sl * 2]; ss += src[sl * 2 + 1]; }
      const float inv = 1.f / (float)(SS * CPG);
      float mean = s * inv;
      float var  = ss * inv - mean * mean;
      stats[bg * 2]     = mean;
      stats[bg * 2 + 1] = rsqrtf(var + EPSV);
    }
    return;
  }
  int which = blockIdx.y;
  const float* W = (which == 0) ? w0 : (which == 1) ? w1 : (which == 2) ? w2 : w3;
  int tx = (blockIdx.x & 3) * 64;
  int ty = (blockIdx.x >> 2) * 64;
  int tid = threadIdx.x;
  int row = tid >> 4;
  int col = (tid & 15) * 4;
#pragma unroll
  for (int i = 0; i < 4; i++) {
    float4 v = *(const float4*)(W + (size_t)(ty + row + i * 16) * CC + tx + col);
    *(float4*)(&t[row + i * 16][col]) = v;
  }
  __syncthreads();
#pragma unroll
  for (int i = 0; i < 4; i++) {
    int n = row + i * 16;
    ushort4 o;
    o.x = f2bf(t[col + 0][n]);
    o.y = f2bf(t[col + 1][n]);
    o.z = f2bf(t[col + 2][n]);
    o.w = f2bf(t[col + 3][n]);
    *(ushort4*)(wt + (size_t)which * CC * CC + (size_t)(tx + n) * CC + ty + col) = o;
  }
}

// ---------------- GroupNorm: normalize -> hn (bf16), 8 ch/thread ----------------
__global__ __launch_bounds__(256) void gn_norm_kernel(const float* __restrict__ x,
                                                      const float* __restrict__ stats,
                                                      const float* __restrict__ gamma,
                                                      const float* __restrict__ beta,
                                                      unsigned short* __restrict__ hn) {
  int i8 = blockIdx.x * 256 + threadIdx.x;
  int c8 = (i8 & 31) * 8;
  size_t row = (size_t)(i8 >> 5);
  int b = (int)(row >> 12);
  int sidx = (b * NG + (c8 >> 3)) * 2;
  float mean = stats[sidx], rstd = stats[sidx + 1];
  const float4* xp = (const float4*)(x + row * CC + c8);
  float4 v0 = xp[0], v1 = xp[1];
  const float4* gp = (const float4*)(gamma + c8);
  float4 g0 = gp[0], g1 = gp[1];
  const float4* bp = (const float4*)(beta + c8);
  float4 b0 = bp[0], b1 = bp[1];
  u16x8 o;
  o[0] = f2bf((v0.x - mean) * rstd * g0.x + b0.x);
  o[1] = f2bf((v0.y - mean) * rstd * g0.y + b0.y);
  o[2] = f2bf((v0.z - mean) * rstd * g0.z + b0.z);
  o[3] = f2bf((v0.w - mean) * rstd * g0.w + b0.w);
  o[4] = f2bf((v1.x - mean) * rstd * g1.x + b1.x);
  o[5] = f2bf((v1.y - mean) * rstd * g1.y + b1.y);
  o[6] = f2bf((v1.z - mean) * rstd * g1.z + b1.z);
  o[7] = f2bf((v1.w - mean) * rstd * g1.w + b1.w);
  *(u16x8*)(hn + row * CC + c8) = o;
}

// ---------------- GEMM v3: B-slab resident + A TRIPLE-buffer, counted vmcnt ----------------
// Tile 256(m) x 64(n), K-step 32, 4 waves each 64x64. Prefetch distance 2:
// at the barrier ending step s, only A(s+1) must be ready -> s_waitcnt vmcnt(4)
// keeps A(s+2)'s 4 DMAs in flight across the barrier. LDS = 80KB -> 2 blocks/CU.

// QKV fused. Outputs: q fp8 (B,S,C) unscaled, k fp8 (B,S,C), v fp8 TRANSPOSED (B,C,S).
__global__ __launch_bounds__(256) void qkv_gemm_kernel(
    const unsigned short* __restrict__ A,
    const unsigned short* __restrict__ WT,
    const float* __restrict__ bq, const float* __restrict__ bk, const float* __restrict__ bv,
    u8* __restrict__ qo, u8* __restrict__ ko, u8* __restrict__ vt) {
  __shared__ __align__(1024) u8 smem[81920];
  u8* A0 = smem;             // 16KB each
  u8* A1 = smem + 16384;
  u8* A2 = smem + 32768;
  u8* Bs = smem + 49152;     // 32KB

  const int which = blockIdx.z;
  const u8* Bwb = (const u8*)(WT + (size_t)which * CC * CC);
  const float* bias = (which == 0) ? bq : (which == 1) ? bk : bv;

  const int m0 = blockIdx.x * 256;
  const int n0 = blockIdx.y * 64;
  const int tid = threadIdx.x;
  const int wave = tid >> 6, lane = tid & 63;
  const int l32 = lane & 31, h = lane >> 5;

  const u8* Ab = (const u8*)A;

  const int am = tid >> 2;
  const int aslot = tid & 3;
  const size_t asrc_row = (size_t)(m0 + am) * 512;
  const int asrc_ch = ((aslot ^ (am & 3)) << 4);
  const int bn = tid >> 5;
  const int bslot = tid & 31;

  // prologue: whole B slab + A steps 0,1 (distance-2 pipeline fill)
#pragma unroll
  for (int i = 0; i < 8; i++) {
    int n = i * 8 + bn;
    dma16(Bwb + (size_t)(n0 + n) * 512 + ((bslot ^ (n & 31)) << 4),
          Bs + i * 4096 + tid * 16);
  }
#pragma unroll
  for (int i = 0; i < 4; i++)
    dma16(Ab + asrc_row + (size_t)i * 64 * 512 + asrc_ch, A0 + i * 4096 + tid * 16);
#pragma unroll
  for (int i = 0; i < 4; i++)
    dma16(Ab + asrc_row + (size_t)i * 64 * 512 + 64 + asrc_ch, A1 + i * 4096 + tid * 16);
  CV_BARRIER(4);   // B + A(0) ready; A(1) still in flight

  f32x16 acc[2][2] = {};
  const int arow0 = (wave * 64 + l32) * 64;
  const int nrow0 = l32 * 512;
  const int aswz = l32 & 3;
  const int bswz = l32;

#pragma unroll
  for (int s = 0; s < 8; ++s) {
    u8* const bufs[3] = {A0, A1, A2};
    u8* cur = bufs[s % 3];             // compile-time after unroll
    if (s + 2 < 8) {
      u8* nxt = bufs[(s + 2) % 3];
      size_t koff = (size_t)(s + 2) * 64;
#pragma unroll
      for (int i = 0; i < 4; i++)
        dma16(Ab + asrc_row + (size_t)i * 64 * 512 + koff + asrc_ch,
              nxt + i * 4096 + tid * 16);
    }
#pragma unroll
    for (int ks = 0; ks < 2; ks++) {
      bf16x8 af0 = *(const bf16x8*)(cur + arow0 + (((h + 2 * ks) ^ aswz) << 4));
      bf16x8 af1 = *(const bf16x8*)(cur + arow0 + 32 * 64 + (((h + 2 * ks) ^ aswz) << 4));
      bf16x8 bf0 = *(const bf16x8*)(Bs + nrow0 + (((s * 4 + h + 2 * ks) ^ bswz) << 4));
      bf16x8 bf1 = *(const bf16x8*)(Bs + nrow0 + 32 * 512 + (((s * 4 + h + 2 * ks) ^ bswz) << 4));
      acc[0][0] = __builtin_amdgcn_mfma_f32_32x32x16_bf16(af0, bf0, acc[0][0], 0, 0, 0);
      acc[0][1] = __builtin_amdgcn_mfma_f32_32x32x16_bf16(af0, bf1, acc[0][1], 0, 0, 0);
      acc[1][0] = __builtin_amdgcn_mfma_f32_32x32x16_bf16(af1, bf0, acc[1][0], 0, 0, 0);
      acc[1][1] = __builtin_amdgcn_mfma_f32_32x32x16_bf16(af1, bf1, acc[1][1], 0, 0, 0);
    }
    if (s < 6)      CV_BARRIER(4);   // A(s+1) ready; A(s+2) in flight
    else if (s < 7) CV_BARRIER(0);   // s==6: drain A(7), nothing newer
    // s==7: no barrier (epilogue reads registers only)
  }

  if (which < 2) {
    u8* out = (which == 0) ? qo : ko;
#pragma unroll
    for (int nt = 0; nt < 2; nt++) {
      int n = n0 + nt * 32 + l32;
      float bv_ = bias[n];
#pragma unroll
      for (int mt = 0; mt < 2; mt++)
#pragma unroll
        for (int r = 0; r < 16; r++) {
          int m = m0 + wave * 64 + mt * 32 + (r & 3) + 8 * (r >> 2) + 4 * h;
          out[(size_t)m * CC + n] = f2fp8(acc[mt][nt][r] + bv_);
        }
    }
  } else {
    int bb = m0 >> 12;
#pragma unroll
    for (int nt = 0; nt < 2; nt++) {
      int n = n0 + nt * 32 + l32;
      float bv_ = bias[n];
#pragma unroll
      for (int mt = 0; mt < 2; mt++)
#pragma unroll
        for (int g = 0; g < 4; g++) {
          int mg = m0 + wave * 64 + mt * 32 + g * 8 + 4 * h;
          int w = __builtin_amdgcn_cvt_pk_fp8_f32(acc[mt][nt][g*4+0] + bv_, acc[mt][nt][g*4+1] + bv_, 0, 0);
          w = __builtin_amdgcn_cvt_pk_fp8_f32(acc[mt][nt][g*4+2] + bv_, acc[mt][nt][g*4+3] + bv_, w, 1);
          *(unsigned int*)(vt + (size_t)bb * CC * SS + (size_t)n * SS + (mg & 4095)) = (unsigned int)w;
        }
    }
  }
}

// Final projection: out = ao @ wo + bo + x  (fp32 out)
__global__ __launch_bounds__(256) void out_gemm_kernel(
    const unsigned short* __restrict__ A,
    const unsigned short* __restrict__ WT,
    const float* __restrict__ bias,
    const float* __restrict__ residual,
    float* __restrict__ Of) {
  __shared__ __align__(1024) u8 smem[81920];
  u8* A0 = smem;
  u8* A1 = smem + 16384;
  u8* A2 = smem + 32768;
  u8* Bs = smem + 49152;

  const u8* Bwb = (const u8*)(WT + (size_t)3 * CC * CC);
  const int m0 = blockIdx.x * 256;
  const int n0 = blockIdx.y * 64;
  const int tid = threadIdx.x;
  const int wave = tid >> 6, lane = tid & 63;
  const int l32 = lane & 31, h = lane >> 5;

  const u8* Ab = (const u8*)A;
  const int am = tid >> 2;
  const int aslot = tid & 3;
  const size_t asrc_row = (size_t)(m0 + am) * 512;
  const int asrc_ch = ((aslot ^ (am & 3)) << 4);
  const int bn = tid >> 5;
  const int bslot = tid & 31;

#pragma unroll
  for (int i = 0; i < 8; i++) {
    int n = i * 8 + bn;
    dma16(Bwb + (size_t)(n0 + n) * 512 + ((bslot ^ (n & 31)) << 4),
          Bs + i * 4096 + tid * 16);
  }
#pragma unroll
  for (int i = 0; i < 4; i++)
    dma16(Ab + asrc_row + (size_t)i * 64 * 512 + asrc_ch, A0 + i * 4096 + tid * 16);
#pragma unroll
  for (int i = 0; i < 4; i++)
    dma16(Ab + asrc_row + (size_t)i * 64 * 512 + 64 + asrc_ch, A1 + i * 4096 + tid * 16);
  CV_BARRIER(4);

  f32x16 acc[2][2] = {};
  const int arow0 = (wave * 64 + l32) * 64;
  const int nrow0 = l32 * 512;
  const int aswz = l32 & 3;
  const int bswz = l32;

#pragma unroll
  for (int s = 0; s < 8; ++s) {
    u8* const bufs[3] = {A0, A1, A2};
    u8* cur = bufs[s % 3];
    if (s + 2 < 8) {
      u8* nxt = bufs[(s + 2) % 3];
      size_t koff = (size_t)(s + 2) * 64;
#pragma unroll
      for (int i = 0; i < 4; i++)
        dma16(Ab + asrc_row + (size_t)i * 64 * 512 + koff + asrc_ch,
              nxt + i * 4096 + tid * 16);
    }
#pragma unroll
    for (int ks = 0; ks < 2; ks++) {
      bf16x8 af0 = *(const bf16x8*)(cur + arow0 + (((h + 2 * ks) ^ aswz) << 4));
      bf16x8 af1 = *(const bf16x8*)(cur + arow0 + 32 * 64 + (((h + 2 * ks) ^ aswz) << 4));
      bf16x8 bf0 = *(const bf16x8*)(Bs + nrow0 + (((s * 4 + h + 2 * ks) ^ bswz) << 4));
      bf16x8 bf1 = *(const bf16x8*)(Bs + nrow0 + 32 * 512 + (((s * 4 + h + 2 * ks) ^ bswz) << 4));
      acc[0][0] = __builtin_amdgcn_mfma_f32_32x32x16_bf16(af0, bf0, acc[0][0], 0, 0, 0);
      acc[0][1] = __builtin_amdgcn_mfma_f32_32x32x16_bf16(af0, bf1, acc[0][1], 0, 0, 0);
      acc[1][0] = __builtin_amdgcn_mfma_f32_32x32x16_bf16(af1, bf0, acc[1][0], 0, 0, 0);
      acc[1][1] = __builtin_amdgcn_mfma_f32_32x32x16_bf16(af1, bf1, acc[1][1], 0, 0, 0);
    }
    if (s < 6)      CV_BARRIER(4);
    else if (s < 7) CV_BARRIER(0);
  }

#pragma unroll
  for (int nt = 0; nt < 2; nt++) {
    int n = n0 + nt * 32 + l32;
    float bv_ = bias[n];
#pragma unroll
    for (int mt = 0; mt < 2; mt++)
#pragma unroll
      for (int r = 0; r < 16; r++) {
        int m = m0 + wave * 64 + mt * 32 + (r & 3) + 8 * (r >> 2) + 4 * h;
        Of[(size_t)m * CC + n] = acc[mt][nt][r] + bv_ + residual[(size_t)m * CC + n];
      }
  }
}

// ---------------- Flash attention v3.1: counted-vmcnt Y-split ----------------
// v3 structure (101.7-106.9us), register-neutral barrier change only:
//  Y1 = vmcnt(8)+barrier (KBb ready; 8 VB stay in flight through QK-B)
//  Y2 = vmcnt(4)+barrier before PV (VB ready; KA(jp+1) prefetch stays in
//       flight through PV). Last iteration: no KA prefetch -> Y2 = vmcnt(0)
//       (else 4 VB loads would still be in flight when PV reads them).
// 128 VGPR + 128 AGPR = exactly 256/wave; do NOT add live state.
#define BR 64

__global__ __launch_bounds__(256, 2) void flash_attn_kernel(
    const u8* __restrict__ Qg,   // (B,S,C) fp8, unscaled
    const u8* __restrict__ Kg,   // (B,S,C) fp8
    const u8* __restrict__ Vtg,  // (B,C,S) fp8
    unsigned short* __restrict__ Og) {
  __shared__ __align__(1024) u8 smem[65536 + 512];
  u8* KA  = smem;
  u8* KBb = smem + 16384;
  u8* VB  = smem + 32768;

  const int bid = blockIdx.x;
  const int b = bid & 7, q0 = (bid >> 3) * BR;
  const int tid = threadIdx.x;
  const int wave = tid >> 6, lane = tid & 63;
  const int l32 = lane & 31, h = lane >> 5;
  const int wm = wave >> 1, wn = wave & 1;   // wm: q-row half, wn: key half

  const u8* Qb  = Qg  + (size_t)b * SS * CC;
  const u8* Kb  = Kg  + (size_t)b * SS * CC;
  const u8* Vtb = Vtg + (size_t)b * CC * SS;

  const int kkey = tid >> 4, kc16 = tid & 15;
  const u8* ksrc0 = Kb + (size_t)kkey * CC + ((kc16 ^ (kkey & 15)) << 4);
  const int vch = tid >> 3;
  const int vs  = (tid & 7) ^ (vch & 7);
  const u8* vsrc0 = Vtb + (size_t)vch * SS + (vs << 4);

  i32x8 qf[4];
  {
    const u8* qrow = Qb + (size_t)(q0 + wm * 32 + l32) * CC + h * 32;
#pragma unroll
    for (int t = 0; t < 4; t++) qf[t] = *(const i32x8*)(qrow + t * 64);
  }

  f32x16 oacc[8] = {};
  float ll = 0.f;

#pragma unroll
  for (int i = 0; i < 4; i++)
    dma16(ksrc0 + (size_t)i * 16 * CC, KA + i * 4096 + tid * 16);

  const int kswz = l32 & 15;
  const int vswz = l32 & 7;

  for (int jp = 0; jp < 32; ++jp) {
    int w0[4], w1[4], o0[4];

    __syncthreads();   // X: KA(jp) drained (had all of PV to land); buffers free
    {
      size_t krow = (size_t)jp * 128 + 64;
#pragma unroll
      for (int i = 0; i < 4; i++)
        dma16(ksrc0 + (krow + (size_t)i * 16) * CC, KBb + i * 4096 + tid * 16);
      size_t vbase = (size_t)jp * 128;
#pragma unroll
      for (int i = 0; i < 8; i++)
        dma16(vsrc0 + (size_t)i * 32 * SS + vbase, VB + i * 4096 + tid * 16);
    }
    {
      f32x16 sacc = {};
      const u8* kb = KA + (wn * 32 + l32) * 256;
      __builtin_amdgcn_s_setprio(1);
#pragma unroll
      for (int t = 0; t < 4; t++) {
        i32x4 r0 = *(const i32x4*)(kb + (((t * 4 + 2 * h)     ^ kswz) << 4));
        i32x4 r1 = *(const i32x4*)(kb + (((t * 4 + 2 * h + 1) ^ kswz) << 4));
        i32x8 kf = __builtin_shufflevector(r0, r1, 0, 1, 2, 3, 4, 5, 6, 7);
        sacc = __builtin_amdgcn_mfma_scale_f32_32x32x64_f8f6f4(
            kf, qf[t], sacc, 0, 0, 0, 0x7F7F7F7F, 0, 0x7F7F7F7F);
      }
      __builtin_amdgcn_s_setprio(0);
#pragma unroll
      for (int g = 0; g < 4; g++) {
        float p0 = fast_exp2(fminf(sacc[g * 4 + 0] * 0.09016844f, 7.213475f));
        float p1 = fast_exp2(fminf(sacc[g * 4 + 1] * 0.09016844f, 7.213475f));
        float p2 = fast_exp2(fminf(sacc[g * 4 + 2] * 0.09016844f, 7.213475f));
        float p3 = fast_exp2(fminf(sacc[g * 4 + 3] * 0.09016844f, 7.213475f));
        ll += (p0 + p1) + (p2 + p3);
        int wv_ = __builtin_amdgcn_cvt_pk_fp8_f32(p0, p1, 0, 0);
        w0[g] = __builtin_amdgcn_cvt_pk_fp8_f32(p2, p3, wv_, 1);
      }
#pragma unroll
      for (int g = 0; g < 4; g++) o0[g] = __shfl_xor(w0[g], 32);
    }

    CV_BARRIER(8);   // Y1: KBb (oldest 4) ready; 8 VB still in flight
    if (jp + 1 < 32) {   // KA(jp+1): all waves past Y1 -> KA reads done
      size_t krow = (size_t)(jp + 1) * 128;
#pragma unroll
      for (int i = 0; i < 4; i++)
        dma16(ksrc0 + (krow + (size_t)i * 16) * CC, KA + i * 4096 + tid * 16);
    }
    {
      f32x16 sacc = {};
      const u8* kb = KBb + (wn * 32 + l32) * 256;
      __builtin_amdgcn_s_setprio(1);
#pragma unroll
      for (int t = 0; t < 4; t++) {
        i32x4 r0 = *(const i32x4*)(kb + (((t * 4 + 2 * h)     ^ kswz) << 4));
        i32x4 r1 = *(const i32x4*)(kb + (((t * 4 + 2 * h + 1) ^ kswz) << 4));
        i32x8 kf = __builtin_shufflevector(r0, r1, 0, 1, 2, 3, 4, 5, 6, 7);
        sacc = __builtin_amdgcn_mfma_scale_f32_32x32x64_f8f6f4(
            kf, qf[t], sacc, 0, 0, 0, 0x7F7F7F7F, 0, 0x7F7F7F7F);
      }
      __builtin_amdgcn_s_setprio(0);
#pragma unroll
      for (int g = 0; g < 4; g++) {
        float p0 = fast_exp2(fminf(sacc[g * 4 + 0] * 0.09016844f, 7.213475f));
        float p1 = fast_exp2(fminf(sacc[g * 4 + 1] * 0.09016844f, 7.213475f));
        float p2 = fast_exp2(fminf(sacc[g * 4 + 2] * 0.09016844f, 7.213475f));
        float p3 = fast_exp2(fminf(sacc[g * 4 + 3] * 0.09016844f, 7.213475f));
        ll += (p0 + p1) + (p2 + p3);
        int wv_ = __builtin_amdgcn_cvt_pk_fp8_f32(p0, p1, 0, 0);
        w1[g] = __builtin_amdgcn_cvt_pk_fp8_f32(p2, p3, wv_, 1);
      }
    }

    int pa_[8];
#pragma unroll
    for (int g = 0; g < 4; g++) {
      int o1 = __shfl_xor(w1[g], 32);
      pa_[2 * g]     = (h == 0) ? w0[g] : o1;
      pa_[2 * g + 1] = (h == 0) ? o0[g] : w1[g];
    }
    i32x8 pa = {pa_[0], pa_[1], pa_[2], pa_[3], pa_[4], pa_[5], pa_[6], pa_[7]};

    // Y2: VB ready; KA(jp+1)'s 4 DMAs ride across PV. Last iter: no KA -> 0.
    if (jp + 1 < 32) CV_BARRIER(4);
    else             CV_BARRIER(0);

    __builtin_amdgcn_s_setprio(1);
#pragma unroll
    for (int nt = 0; nt < 8; nt++) {
      const u8* vb = VB + (nt * 32 + l32) * 128;
      i32x4 r0 = *(const i32x4*)(vb + (((4 * h + 2 * wn)     ^ vswz) << 4));
      i32x4 r1 = *(const i32x4*)(vb + (((4 * h + 2 * wn + 1) ^ vswz) << 4));
      i32x8 vf = __builtin_shufflevector(r0, r1, 0, 1, 2, 3, 4, 5, 6, 7);
      oacc[nt] = __builtin_amdgcn_mfma_scale_f32_32x32x64_f8f6f4(
          pa, vf, oacc[nt], 0, 0, 0, 0x7F7F7F7F, 0, 0x7F7F7F7F);
    }
    __builtin_amdgcn_s_setprio(0);
  }

  __syncthreads();
  ll += __shfl_xor(ll, 32);
  float* Lred = (float*)(smem + 65536);
  if (h == 0) Lred[wn * 64 + wm * 32 + l32] = ll;

  float* scratch = (float*)smem;
  {
    float* z = scratch + (size_t)(wm * 2 + (1 - wn)) * 4096;
#pragma unroll
    for (int ntg = 0; ntg < 8; ntg++) {
      if ((ntg >> 2) != wn) {
        int nt = ntg & 3;
#pragma unroll
        for (int r = 0; r < 16; r++) {
          int row = (r & 3) + 8 * (r >> 2) + 4 * h;
          z[row * 128 + nt * 32 + l32] = oacc[ntg][r];
        }
      }
    }
  }
  __syncthreads();
  {
    const float* z = scratch + (size_t)(wm * 2 + wn) * 4096;
#pragma unroll
    for (int ntg = 0; ntg < 8; ntg++) {
      if ((ntg >> 2) == wn) {
        int nt = ntg & 3;
#pragma unroll
        for (int r = 0; r < 16; r++) {
          int row = (r & 3) + 8 * (r >> 2) + 4 * h;
          float inv = 1.f / (Lred[wm * 32 + row] + Lred[64 + wm * 32 + row]);
          float v = oacc[ntg][r] + z[row * 128 + nt * 32 + l32];
          Og[((size_t)b * SS + q0 + wm * 32 + row) * CC + wn * 128 + nt * 32 + l32]
              = f2bf(v * inv);
        }
      }
    }
  }
}

// ---------------- launch ----------------
extern "C" void kernel_launch(void* const* d_in, const int* in_sizes, int n_in,
                              void* d_out, int out_size, void* d_ws, size_t ws_size,
                              hipStream_t stream) {
  const float* x   = (const float*)d_in[0];
  const float* gsc = (const float*)d_in[1];
  const float* gbi = (const float*)d_in[2];
  const float* wq  = (const float*)d_in[3];
  const float* bq  = (const float*)d_in[4];
  const float* wk  = (const float*)d_in[5];
  const float* bk  = (const float*)d_in[6];
  const float* wv  = (const float*)d_in[7];
  const float* bv  = (const float*)d_in[8];
  const float* wo  = (const float*)d_in[9];
  const float* bo  = (const float*)d_in[10];
  float* out = (float*)d_out;

  // workspace: stats | wt(bf16) | hn(bf16) | ao(bf16) | q(fp8) | k(fp8) | vt(fp8)
  char* ws = (char*)d_ws;
  const size_t MAT = (size_t)MTOT * CC;
  float* stats        = (float*)ws;
  unsigned short* wt  = (unsigned short*)(ws + 4096);
  unsigned short* hn  = wt + (size_t)4 * CC * CC;
  unsigned short* ao  = hn + MAT;
  u8* q  = (u8*)(ao + MAT);
  u8* k  = q + MAT;
  u8* vt = k + MAT;

  // gn_stats partials (64KB) alias the ao region (written only by flash, later)
  float* part = (float*)ao;

  gn_stats_part_kernel<<<NB * NG, 256, 0, stream>>>(x, part);
  prep_wt_kernel<<<dim3(16, 5), 256, 0, stream>>>(wq, wk, wv, wo, wt, part, stats);
  gn_norm_kernel<<<(int)(MAT / 8 / 256), 256, 0, stream>>>(x, stats, gsc, gbi, hn);

  qkv_gemm_kernel<<<dim3(MTOT / 256, CC / 64, 3), 256, 0, stream>>>(
      hn, wt, bq, bk, bv, q, k, vt);

  flash_attn_kernel<<<NB * (SS / BR), 256, 0, stream>>>(q, k, vt, ao);

  out_gemm_kernel<<<dim3(MTOT / 256, CC / 64), 256, 0, stream>>>(ao, wt, bo, x, out);
}

// Round 11
// 241.568 us; speedup vs baseline: 1.0183x; 1.0183x over previous
//
#include <hip/hip_runtime.h>

// Problem constants (B,H,W,C = 8,64,64,256; S = H*W)
#define NB   8
#define SS   4096
#define CC   256
#define NG   32
#define CPG  8
#define EPSV 1e-6f
#define MTOT (NB * SS)   // 32768 rows

typedef short bf16x8 __attribute__((ext_vector_type(8)));
typedef unsigned short u16x8 __attribute__((ext_vector_type(8)));
typedef float f32x4  __attribute__((ext_vector_type(4)));
typedef float f32x16 __attribute__((ext_vector_type(16)));
typedef int   i32x4  __attribute__((ext_vector_type(4)));
typedef int   i32x8  __attribute__((ext_vector_type(8)));
typedef unsigned char u8;

typedef __attribute__((address_space(1))) const unsigned int as1_u32;
typedef __attribute__((address_space(3))) unsigned int as3_u32;

__device__ __forceinline__ unsigned short f2bf(float f) {
  unsigned int u = __builtin_bit_cast(unsigned int, f);
  u = (u + 0x7FFFu + ((u >> 16) & 1u)) >> 16;
  return (unsigned short)u;
}
__device__ __forceinline__ u8 f2fp8(float f) {
  return (u8)(__builtin_amdgcn_cvt_pk_fp8_f32(f, f, 0, 0) & 0xFF);
}
__device__ __forceinline__ void dma16(const u8* src, u8* lds) {
  __builtin_amdgcn_global_load_lds((as1_u32*)src, (as3_u32*)lds, 16, 0, 0);
}
__device__ __forceinline__ float fast_exp2(float x) {
#if __has_builtin(__builtin_amdgcn_exp2f)
  return __builtin_amdgcn_exp2f(x);   // bare v_exp_f32
#else
  return exp2f(x);
#endif
}

// Counted-vmcnt barrier (T3/T4): each wave waits its OWN oldest DMAs (FIFO,
// m135), THEN crosses the barrier -> all waves' counted loads visible in LDS.
// sched_barrier pins ordering (rule 18).
#define CV_BARRIER(N)                                              \
  do {                                                             \
    asm volatile("s_waitcnt vmcnt(" #N ")" ::: "memory");          \
    __builtin_amdgcn_s_barrier();                                  \
    __builtin_amdgcn_sched_barrier(0);                             \
  } while (0)

// ---------------- GroupNorm stats, stage 1: coalesced partials ----------------
__global__ __launch_bounds__(256) void gn_stats_part_kernel(
    const float* __restrict__ x, float* __restrict__ part) {
  const int b = blockIdx.x >> 5, slice = blockIdx.x & 31;
  const int tid = threadIdx.x;
  const int g = tid & 31;            // group
  const int p8 = tid >> 5;           // pos sub-index 0..7
  const float* base = x + ((size_t)(b * SS + slice * 128 + p8) * CC + g * CPG);
  float s = 0.f, ss = 0.f;
#pragma unroll
  for (int it = 0; it < 16; it++) {
    const float4* p = (const float4*)(base + (size_t)it * 8 * CC);
    float4 a = p[0], c = p[1];
    s  += (a.x + a.y) + (a.z + a.w) + (c.x + c.y) + (c.z + c.w);
    ss += (a.x*a.x + a.y*a.y) + (a.z*a.z + a.w*a.w)
        + (c.x*c.x + c.y*c.y) + (c.z*c.z + c.w*c.w);
  }
  s  += __shfl_xor(s, 32);
  ss += __shfl_xor(ss, 32);
  __shared__ float lsum[4][32], lssum[4][32];
  const int wv = tid >> 6, lane = tid & 63;
  if (lane < 32) { lsum[wv][lane] = s; lssum[wv][lane] = ss; }
  __syncthreads();
  if (tid < 32) {
    float ts  = (lsum[0][tid] + lsum[1][tid]) + (lsum[2][tid] + lsum[3][tid]);
    float tss = (lssum[0][tid] + lssum[1][tid]) + (lssum[2][tid] + lssum[3][tid]);
    float* dst = part + ((size_t)(b * 32 + tid) * 32 + slice) * 2;
    dst[0] = ts; dst[1] = tss;
  }
}

// ---------------- Weight prep (+ fused gn_stats finalize at y==4) ----------------
__global__ __launch_bounds__(256) void prep_wt_kernel(
    const float* __restrict__ w0, const float* __restrict__ w1,
    const float* __restrict__ w2, const float* __restrict__ w3,
    unsigned short* __restrict__ wt,
    const float* __restrict__ part, float* __restrict__ stats) {
  __shared__ float t[64][68];
  if (blockIdx.y == 4) {
    if (blockIdx.x == 0) {
      const int bg = threadIdx.x;   // b*32+g, 0..255
      const float* src = part + (size_t)bg * 64;
      float s = 0.f, ss = 0.f;
#pragma unroll
      for (int sl = 0; sl < 32; sl++) { s += src[sl * 2]; ss += src[sl * 2 + 1]; }
      const float inv = 1.f / (float)(SS * CPG);
      float mean = s * inv;
      float var  = ss * inv - mean * mean;
      stats[bg * 2]     = mean;
      stats[bg * 2 + 1] = rsqrtf(var + EPSV);
    }
    return;
  }
  int which = blockIdx.y;
  const float* W = (which == 0) ? w0 : (which == 1) ? w1 : (which == 2) ? w2 : w3;
  int tx = (blockIdx.x & 3) * 64;
  int ty = (blockIdx.x >> 2) * 64;
  int tid = threadIdx.x;
  int row = tid >> 4;
  int col = (tid & 15) * 4;
#pragma unroll
  for (int i = 0; i < 4; i++) {
    float4 v = *(const float4*)(W + (size_t)(ty + row + i * 16) * CC + tx + col);
    *(float4*)(&t[row + i * 16][col]) = v;
  }
  __syncthreads();
#pragma unroll
  for (int i = 0; i < 4; i++) {
    int n = row + i * 16;
    ushort4 o;
    o.x = f2bf(t[col + 0][n]);
    o.y = f2bf(t[col + 1][n]);
    o.z = f2bf(t[col + 2][n]);
    o.w = f2bf(t[col + 3][n]);
    *(ushort4*)(wt + (size_t)which * CC * CC + (size_t)(tx + n) * CC + ty + col) = o;
  }
}

// ---------------- GroupNorm: normalize -> hn (bf16), 8 ch/thread ----------------
__global__ __launch_bounds__(256) void gn_norm_kernel(const float* __restrict__ x,
                                                      const float* __restrict__ stats,
                                                      const float* __restrict__ gamma,
                                                      const float* __restrict__ beta,
                                                      unsigned short* __restrict__ hn) {
  int i8 = blockIdx.x * 256 + threadIdx.x;
  int c8 = (i8 & 31) * 8;
  size_t row = (size_t)(i8 >> 5);
  int b = (int)(row >> 12);
  int sidx = (b * NG + (c8 >> 3)) * 2;
  float mean = stats[sidx], rstd = stats[sidx + 1];
  const float4* xp = (const float4*)(x + row * CC + c8);
  float4 v0 = xp[0], v1 = xp[1];
  const float4* gp = (const float4*)(gamma + c8);
  float4 g0 = gp[0], g1 = gp[1];
  const float4* bp = (const float4*)(beta + c8);
  float4 b0 = bp[0], b1 = bp[1];
  u16x8 o;
  o[0] = f2bf((v0.x - mean) * rstd * g0.x + b0.x);
  o[1] = f2bf((v0.y - mean) * rstd * g0.y + b0.y);
  o[2] = f2bf((v0.z - mean) * rstd * g0.z + b0.z);
  o[3] = f2bf((v0.w - mean) * rstd * g0.w + b0.w);
  o[4] = f2bf((v1.x - mean) * rstd * g1.x + b1.x);
  o[5] = f2bf((v1.y - mean) * rstd * g1.y + b1.y);
  o[6] = f2bf((v1.z - mean) * rstd * g1.z + b1.z);
  o[7] = f2bf((v1.w - mean) * rstd * g1.w + b1.w);
  *(u16x8*)(hn + row * CC + c8) = o;
}

// ---------------- GEMM v3: B-slab resident + A TRIPLE-buffer, counted vmcnt ----------------
// Tile 256(m) x 64(n), K-step 32, 4 waves each 64x64. Prefetch distance 2:
// at the barrier ending step s, only A(s+1) must be ready -> s_waitcnt vmcnt(4)
// keeps A(s+2)'s 4 DMAs in flight across the barrier. LDS = 80KB -> 2 blocks/CU.

// QKV fused. Outputs: q fp8 (B,S,C) unscaled, k fp8 (B,S,C), v fp8 TRANSPOSED (B,C,S).
__global__ __launch_bounds__(256) void qkv_gemm_kernel(
    const unsigned short* __restrict__ A,
    const unsigned short* __restrict__ WT,
    const float* __restrict__ bq, const float* __restrict__ bk, const float* __restrict__ bv,
    u8* __restrict__ qo, u8* __restrict__ ko, u8* __restrict__ vt) {
  __shared__ __align__(1024) u8 smem[81920];
  u8* A0 = smem;             // 16KB each
  u8* A1 = smem + 16384;
  u8* A2 = smem + 32768;
  u8* Bs = smem + 49152;     // 32KB

  const int which = blockIdx.z;
  const u8* Bwb = (const u8*)(WT + (size_t)which * CC * CC);
  const float* bias = (which == 0) ? bq : (which == 1) ? bk : bv;

  const int m0 = blockIdx.x * 256;
  const int n0 = blockIdx.y * 64;
  const int tid = threadIdx.x;
  const int wave = tid >> 6, lane = tid & 63;
  const int l32 = lane & 31, h = lane >> 5;

  const u8* Ab = (const u8*)A;

  const int am = tid >> 2;
  const int aslot = tid & 3;
  const size_t asrc_row = (size_t)(m0 + am) * 512;
  const int asrc_ch = ((aslot ^ (am & 3)) << 4);
  const int bn = tid >> 5;
  const int bslot = tid & 31;

  // prologue: whole B slab + A steps 0,1 (distance-2 pipeline fill)
#pragma unroll
  for (int i = 0; i < 8; i++) {
    int n = i * 8 + bn;
    dma16(Bwb + (size_t)(n0 + n) * 512 + ((bslot ^ (n & 31)) << 4),
          Bs + i * 4096 + tid * 16);
  }
#pragma unroll
  for (int i = 0; i < 4; i++)
    dma16(Ab + asrc_row + (size_t)i * 64 * 512 + asrc_ch, A0 + i * 4096 + tid * 16);
#pragma unroll
  for (int i = 0; i < 4; i++)
    dma16(Ab + asrc_row + (size_t)i * 64 * 512 + 64 + asrc_ch, A1 + i * 4096 + tid * 16);
  CV_BARRIER(4);   // B + A(0) ready; A(1) still in flight

  f32x16 acc[2][2] = {};
  const int arow0 = (wave * 64 + l32) * 64;
  const int nrow0 = l32 * 512;
  const int aswz = l32 & 3;
  const int bswz = l32;

#pragma unroll
  for (int s = 0; s < 8; ++s) {
    u8* const bufs[3] = {A0, A1, A2};
    u8* cur = bufs[s % 3];             // compile-time after unroll
    if (s + 2 < 8) {
      u8* nxt = bufs[(s + 2) % 3];
      size_t koff = (size_t)(s + 2) * 64;
#pragma unroll
      for (int i = 0; i < 4; i++)
        dma16(Ab + asrc_row + (size_t)i * 64 * 512 + koff + asrc_ch,
              nxt + i * 4096 + tid * 16);
    }
#pragma unroll
    for (int ks = 0; ks < 2; ks++) {
      bf16x8 af0 = *(const bf16x8*)(cur + arow0 + (((h + 2 * ks) ^ aswz) << 4));
      bf16x8 af1 = *(const bf16x8*)(cur + arow0 + 32 * 64 + (((h + 2 * ks) ^ aswz) << 4));
      bf16x8 bf0 = *(const bf16x8*)(Bs + nrow0 + (((s * 4 + h + 2 * ks) ^ bswz) << 4));
      bf16x8 bf1 = *(const bf16x8*)(Bs + nrow0 + 32 * 512 + (((s * 4 + h + 2 * ks) ^ bswz) << 4));
      acc[0][0] = __builtin_amdgcn_mfma_f32_32x32x16_bf16(af0, bf0, acc[0][0], 0, 0, 0);
      acc[0][1] = __builtin_amdgcn_mfma_f32_32x32x16_bf16(af0, bf1, acc[0][1], 0, 0, 0);
      acc[1][0] = __builtin_amdgcn_mfma_f32_32x32x16_bf16(af1, bf0, acc[1][0], 0, 0, 0);
      acc[1][1] = __builtin_amdgcn_mfma_f32_32x32x16_bf16(af1, bf1, acc[1][1], 0, 0, 0);
    }
    if (s < 6)      CV_BARRIER(4);   // A(s+1) ready; A(s+2) in flight
    else if (s < 7) CV_BARRIER(0);   // s==6: drain A(7), nothing newer
    // s==7: no barrier (epilogue reads registers only)
  }

  if (which < 2) {
    u8* out = (which == 0) ? qo : ko;
#pragma unroll
    for (int nt = 0; nt < 2; nt++) {
      int n = n0 + nt * 32 + l32;
      float bv_ = bias[n];
#pragma unroll
      for (int mt = 0; mt < 2; mt++)
#pragma unroll
        for (int r = 0; r < 16; r++) {
          int m = m0 + wave * 64 + mt * 32 + (r & 3) + 8 * (r >> 2) + 4 * h;
          out[(size_t)m * CC + n] = f2fp8(acc[mt][nt][r] + bv_);
        }
    }
  } else {
    int bb = m0 >> 12;
#pragma unroll
    for (int nt = 0; nt < 2; nt++) {
      int n = n0 + nt * 32 + l32;
      float bv_ = bias[n];
#pragma unroll
      for (int mt = 0; mt < 2; mt++)
#pragma unroll
        for (int g = 0; g < 4; g++) {
          int mg = m0 + wave * 64 + mt * 32 + g * 8 + 4 * h;
          int w = __builtin_amdgcn_cvt_pk_fp8_f32(acc[mt][nt][g*4+0] + bv_, acc[mt][nt][g*4+1] + bv_, 0, 0);
          w = __builtin_amdgcn_cvt_pk_fp8_f32(acc[mt][nt][g*4+2] + bv_, acc[mt][nt][g*4+3] + bv_, w, 1);
          *(unsigned int*)(vt + (size_t)bb * CC * SS + (size_t)n * SS + (mg & 4095)) = (unsigned int)w;
        }
    }
  }
}

// Final projection: out = ao @ wo + bo + x  (fp32 out)
__global__ __launch_bounds__(256) void out_gemm_kernel(
    const unsigned short* __restrict__ A,
    const unsigned short* __restrict__ WT,
    const float* __restrict__ bias,
    const float* __restrict__ residual,
    float* __restrict__ Of) {
  __shared__ __align__(1024) u8 smem[81920];
  u8* A0 = smem;
  u8* A1 = smem + 16384;
  u8* A2 = smem + 32768;
  u8* Bs = smem + 49152;

  const u8* Bwb = (const u8*)(WT + (size_t)3 * CC * CC);
  const int m0 = blockIdx.x * 256;
  const int n0 = blockIdx.y * 64;
  const int tid = threadIdx.x;
  const int wave = tid >> 6, lane = tid & 63;
  const int l32 = lane & 31, h = lane >> 5;

  const u8* Ab = (const u8*)A;
  const int am = tid >> 2;
  const int aslot = tid & 3;
  const size_t asrc_row = (size_t)(m0 + am) * 512;
  const int asrc_ch = ((aslot ^ (am & 3)) << 4);
  const int bn = tid >> 5;
  const int bslot = tid & 31;

#pragma unroll
  for (int i = 0; i < 8; i++) {
    int n = i * 8 + bn;
    dma16(Bwb + (size_t)(n0 + n) * 512 + ((bslot ^ (n & 31)) << 4),
          Bs + i * 4096 + tid * 16);
  }
#pragma unroll
  for (int i = 0; i < 4; i++)
    dma16(Ab + asrc_row + (size_t)i * 64 * 512 + asrc_ch, A0 + i * 4096 + tid * 16);
#pragma unroll
  for (int i = 0; i < 4; i++)
    dma16(Ab + asrc_row + (size_t)i * 64 * 512 + 64 + asrc_ch, A1 + i * 4096 + tid * 16);
  CV_BARRIER(4);

  f32x16 acc[2][2] = {};
  const int arow0 = (wave * 64 + l32) * 64;
  const int nrow0 = l32 * 512;
  const int aswz = l32 & 3;
  const int bswz = l32;

#pragma unroll
  for (int s = 0; s < 8; ++s) {
    u8* const bufs[3] = {A0, A1, A2};
    u8* cur = bufs[s % 3];
    if (s + 2 < 8) {
      u8* nxt = bufs[(s + 2) % 3];
      size_t koff = (size_t)(s + 2) * 64;
#pragma unroll
      for (int i = 0; i < 4; i++)
        dma16(Ab + asrc_row + (size_t)i * 64 * 512 + koff + asrc_ch,
              nxt + i * 4096 + tid * 16);
    }
#pragma unroll
    for (int ks = 0; ks < 2; ks++) {
      bf16x8 af0 = *(const bf16x8*)(cur + arow0 + (((h + 2 * ks) ^ aswz) << 4));
      bf16x8 af1 = *(const bf16x8*)(cur + arow0 + 32 * 64 + (((h + 2 * ks) ^ aswz) << 4));
      bf16x8 bf0 = *(const bf16x8*)(Bs + nrow0 + (((s * 4 + h + 2 * ks) ^ bswz) << 4));
      bf16x8 bf1 = *(const bf16x8*)(Bs + nrow0 + 32 * 512 + (((s * 4 + h + 2 * ks) ^ bswz) << 4));
      acc[0][0] = __builtin_amdgcn_mfma_f32_32x32x16_bf16(af0, bf0, acc[0][0], 0, 0, 0);
      acc[0][1] = __builtin_amdgcn_mfma_f32_32x32x16_bf16(af0, bf1, acc[0][1], 0, 0, 0);
      acc[1][0] = __builtin_amdgcn_mfma_f32_32x32x16_bf16(af1, bf0, acc[1][0], 0, 0, 0);
      acc[1][1] = __builtin_amdgcn_mfma_f32_32x32x16_bf16(af1, bf1, acc[1][1], 0, 0, 0);
    }
    if (s < 6)      CV_BARRIER(4);
    else if (s < 7) CV_BARRIER(0);
  }

#pragma unroll
  for (int nt = 0; nt < 2; nt++) {
    int n = n0 + nt * 32 + l32;
    float bv_ = bias[n];
#pragma unroll
    for (int mt = 0; mt < 2; mt++)
#pragma unroll
      for (int r = 0; r < 16; r++) {
        int m = m0 + wave * 64 + mt * 32 + (r & 3) + 8 * (r >> 2) + 4 * h;
        Of[(size_t)m * CC + n] = acc[mt][nt][r] + bv_ + residual[(size_t)m * CC + n];
      }
  }
}

// ---------------- Flash attention v3 (best-known; 101.7-106.9us band) ----------------
// Register budget: per-SIMD unified file = 512 regs/wave at 2 waves/SIMD.
// This kernel = 128 VGPR + 128 AGPR = exactly 256/wave. Structural limit:
// MFMA-busy ~29us = MX-fp8 pipe floor; occupancy restructures (v4/v5/v6) and
// counted-vmcnt Y-split (r10) all null or regressed. Do NOT add live state.
#define BR 64

__global__ __launch_bounds__(256, 2) void flash_attn_kernel(
    const u8* __restrict__ Qg,   // (B,S,C) fp8, unscaled
    const u8* __restrict__ Kg,   // (B,S,C) fp8
    const u8* __restrict__ Vtg,  // (B,C,S) fp8
    unsigned short* __restrict__ Og) {
  __shared__ __align__(1024) u8 smem[65536 + 512];
  u8* KA  = smem;
  u8* KBb = smem + 16384;
  u8* VB  = smem + 32768;

  const int bid = blockIdx.x;
  const int b = bid & 7, q0 = (bid >> 3) * BR;
  const int tid = threadIdx.x;
  const int wave = tid >> 6, lane = tid & 63;
  const int l32 = lane & 31, h = lane >> 5;
  const int wm = wave >> 1, wn = wave & 1;   // wm: q-row half, wn: key half

  const u8* Qb  = Qg  + (size_t)b * SS * CC;
  const u8* Kb  = Kg  + (size_t)b * SS * CC;
  const u8* Vtb = Vtg + (size_t)b * CC * SS;

  const int kkey = tid >> 4, kc16 = tid & 15;
  const u8* ksrc0 = Kb + (size_t)kkey * CC + ((kc16 ^ (kkey & 15)) << 4);
  const int vch = tid >> 3;
  const int vs  = (tid & 7) ^ (vch & 7);
  const u8* vsrc0 = Vtb + (size_t)vch * SS + (vs << 4);

  i32x8 qf[4];
  {
    const u8* qrow = Qb + (size_t)(q0 + wm * 32 + l32) * CC + h * 32;
#pragma unroll
    for (int t = 0; t < 4; t++) qf[t] = *(const i32x8*)(qrow + t * 64);
  }

  f32x16 oacc[8] = {};
  float ll = 0.f;

#pragma unroll
  for (int i = 0; i < 4; i++)
    dma16(ksrc0 + (size_t)i * 16 * CC, KA + i * 4096 + tid * 16);

  const int kswz = l32 & 15;
  const int vswz = l32 & 7;

  for (int jp = 0; jp < 32; ++jp) {
    int w0[4], w1[4], o0[4];

    __syncthreads();
    {
      size_t krow = (size_t)jp * 128 + 64;
#pragma unroll
      for (int i = 0; i < 4; i++)
        dma16(ksrc0 + (krow + (size_t)i * 16) * CC, KBb + i * 4096 + tid * 16);
      size_t vbase = (size_t)jp * 128;
#pragma unroll
      for (int i = 0; i < 8; i++)
        dma16(vsrc0 + (size_t)i * 32 * SS + vbase, VB + i * 4096 + tid * 16);
    }
    {
      f32x16 sacc = {};
      const u8* kb = KA + (wn * 32 + l32) * 256;
      __builtin_amdgcn_s_setprio(1);
#pragma unroll
      for (int t = 0; t < 4; t++) {
        i32x4 r0 = *(const i32x4*)(kb + (((t * 4 + 2 * h)     ^ kswz) << 4));
        i32x4 r1 = *(const i32x4*)(kb + (((t * 4 + 2 * h + 1) ^ kswz) << 4));
        i32x8 kf = __builtin_shufflevector(r0, r1, 0, 1, 2, 3, 4, 5, 6, 7);
        sacc = __builtin_amdgcn_mfma_scale_f32_32x32x64_f8f6f4(
            kf, qf[t], sacc, 0, 0, 0, 0x7F7F7F7F, 0, 0x7F7F7F7F);
      }
      __builtin_amdgcn_s_setprio(0);
#pragma unroll
      for (int g = 0; g < 4; g++) {
        float p0 = fast_exp2(fminf(sacc[g * 4 + 0] * 0.09016844f, 7.213475f));
        float p1 = fast_exp2(fminf(sacc[g * 4 + 1] * 0.09016844f, 7.213475f));
        float p2 = fast_exp2(fminf(sacc[g * 4 + 2] * 0.09016844f, 7.213475f));
        float p3 = fast_exp2(fminf(sacc[g * 4 + 3] * 0.09016844f, 7.213475f));
        ll += (p0 + p1) + (p2 + p3);
        int wv_ = __builtin_amdgcn_cvt_pk_fp8_f32(p0, p1, 0, 0);
        w0[g] = __builtin_amdgcn_cvt_pk_fp8_f32(p2, p3, wv_, 1);
      }
#pragma unroll
      for (int g = 0; g < 4; g++) o0[g] = __shfl_xor(w0[g], 32);
    }

    __syncthreads();
    if (jp + 1 < 32) {
      size_t krow = (size_t)(jp + 1) * 128;
#pragma unroll
      for (int i = 0; i < 4; i++)
        dma16(ksrc0 + (krow + (size_t)i * 16) * CC, KA + i * 4096 + tid * 16);
    }
    {
      f32x16 sacc = {};
      const u8* kb = KBb + (wn * 32 + l32) * 256;
      __builtin_amdgcn_s_setprio(1);
#pragma unroll
      for (int t = 0; t < 4; t++) {
        i32x4 r0 = *(const i32x4*)(kb + (((t * 4 + 2 * h)     ^ kswz) << 4));
        i32x4 r1 = *(const i32x4*)(kb + (((t * 4 + 2 * h + 1) ^ kswz) << 4));
        i32x8 kf = __builtin_shufflevector(r0, r1, 0, 1, 2, 3, 4, 5, 6, 7);
        sacc = __builtin_amdgcn_mfma_scale_f32_32x32x64_f8f6f4(
            kf, qf[t], sacc, 0, 0, 0, 0x7F7F7F7F, 0, 0x7F7F7F7F);
      }
      __builtin_amdgcn_s_setprio(0);
#pragma unroll
      for (int g = 0; g < 4; g++) {
        float p0 = fast_exp2(fminf(sacc[g * 4 + 0] * 0.09016844f, 7.213475f));
        float p1 = fast_exp2(fminf(sacc[g * 4 + 1] * 0.09016844f, 7.213475f));
        float p2 = fast_exp2(fminf(sacc[g * 4 + 2] * 0.09016844f, 7.213475f));
        float p3 = fast_exp2(fminf(sacc[g * 4 + 3] * 0.09016844f, 7.213475f));
        ll += (p0 + p1) + (p2 + p3);
        int wv_ = __builtin_amdgcn_cvt_pk_fp8_f32(p0, p1, 0, 0);
        w1[g] = __builtin_amdgcn_cvt_pk_fp8_f32(p2, p3, wv_, 1);
      }
    }

    int pa_[8];
#pragma unroll
    for (int g = 0; g < 4; g++) {
      int o1 = __shfl_xor(w1[g], 32);
      pa_[2 * g]     = (h == 0) ? w0[g] : o1;
      pa_[2 * g + 1] = (h == 0) ? o0[g] : w1[g];
    }
    i32x8 pa = {pa_[0], pa_[1], pa_[2], pa_[3], pa_[4], pa_[5], pa_[6], pa_[7]};

    __builtin_amdgcn_s_setprio(1);
#pragma unroll
    for (int nt = 0; nt < 8; nt++) {
      const u8* vb = VB + (nt * 32 + l32) * 128;
      i32x4 r0 = *(const i32x4*)(vb + (((4 * h + 2 * wn)     ^ vswz) << 4));
      i32x4 r1 = *(const i32x4*)(vb + (((4 * h + 2 * wn + 1) ^ vswz) << 4));
      i32x8 vf = __builtin_shufflevector(r0, r1, 0, 1, 2, 3, 4, 5, 6, 7);
      oacc[nt] = __builtin_amdgcn_mfma_scale_f32_32x32x64_f8f6f4(
          pa, vf, oacc[nt], 0, 0, 0, 0x7F7F7F7F, 0, 0x7F7F7F7F);
    }
    __builtin_amdgcn_s_setprio(0);
  }

  __syncthreads();
  ll += __shfl_xor(ll, 32);
  float* Lred = (float*)(smem + 65536);
  if (h == 0) Lred[wn * 64 + wm * 32 + l32] = ll;

  float* scratch = (float*)smem;
  {
    float* z = scratch + (size_t)(wm * 2 + (1 - wn)) * 4096;
#pragma unroll
    for (int ntg = 0; ntg < 8; ntg++) {
      if ((ntg >> 2) != wn) {
        int nt = ntg & 3;
#pragma unroll
        for (int r = 0; r < 16; r++) {
          int row = (r & 3) + 8 * (r >> 2) + 4 * h;
          z[row * 128 + nt * 32 + l32] = oacc[ntg][r];
        }
      }
    }
  }
  __syncthreads();
  {
    const float* z = scratch + (size_t)(wm * 2 + wn) * 4096;
#pragma unroll
    for (int ntg = 0; ntg < 8; ntg++) {
      if ((ntg >> 2) == wn) {
        int nt = ntg & 3;
#pragma unroll
        for (int r = 0; r < 16; r++) {
          int row = (r & 3) + 8 * (r >> 2) + 4 * h;
          float inv = 1.f / (Lred[wm * 32 + row] + Lred[64 + wm * 32 + row]);
          float v = oacc[ntg][r] + z[row * 128 + nt * 32 + l32];
          Og[((size_t)b * SS + q0 + wm * 32 + row) * CC + wn * 128 + nt * 32 + l32]
              = f2bf(v * inv);
        }
      }
    }
  }
}

// ---------------- launch ----------------
extern "C" void kernel_launch(void* const* d_in, const int* in_sizes, int n_in,
                              void* d_out, int out_size, void* d_ws, size_t ws_size,
                              hipStream_t stream) {
  const float* x   = (const float*)d_in[0];
  const float* gsc = (const float*)d_in[1];
  const float* gbi = (const float*)d_in[2];
  const float* wq  = (const float*)d_in[3];
  const float* bq  = (const float*)d_in[4];
  const float* wk  = (const float*)d_in[5];
  const float* bk  = (const float*)d_in[6];
  const float* wv  = (const float*)d_in[7];
  const float* bv  = (const float*)d_in[8];
  const float* wo  = (const float*)d_in[9];
  const float* bo  = (const float*)d_in[10];
  float* out = (float*)d_out;

  // workspace: stats | wt(bf16) | hn(bf16) | ao(bf16) | q(fp8) | k(fp8) | vt(fp8)
  char* ws = (char*)d_ws;
  const size_t MAT = (size_t)MTOT * CC;
  float* stats        = (float*)ws;
  unsigned short* wt  = (unsigned short*)(ws + 4096);
  unsigned short* hn  = wt + (size_t)4 * CC * CC;
  unsigned short* ao  = hn + MAT;
  u8* q  = (u8*)(ao + MAT);
  u8* k  = q + MAT;
  u8* vt = k + MAT;

  // gn_stats partials (64KB) alias the ao region (written only by flash, later)
  float* part = (float*)ao;

  gn_stats_part_kernel<<<NB * NG, 256, 0, stream>>>(x, part);
  prep_wt_kernel<<<dim3(16, 5), 256, 0, stream>>>(wq, wk, wv, wo, wt, part, stats);
  gn_norm_kernel<<<(int)(MAT / 8 / 256), 256, 0, stream>>>(x, stats, gsc, gbi, hn);

  qkv_gemm_kernel<<<dim3(MTOT / 256, CC / 64, 3), 256, 0, stream>>>(
      hn, wt, bq, bk, bv, q, k, vt);

  flash_attn_kernel<<<NB * (SS / BR), 256, 0, stream>>>(q, k, vt, ao);

  out_gemm_kernel<<<dim3(MTOT / 256, CC / 64), 256, 0, stream>>>(ao, wt, bo, x, out);
}